// Round 4
// baseline (274.987 us; speedup 1.0000x reference)
//
#include <hip/hip_runtime.h>
#include <hip/hip_bf16.h>

// CRF broadcast-add: out[b,l,i,j] = emission[b,l,j] + transition[i,j]
// B=32, L=512, T=64, fp32. Output = 256 MiB -> pure write-BW bound.
// Roofline: (256 MiB store + 4 MiB load) / 6.4 TB/s ~= 42 us (fill-rate).
//
// v4: one block per (b,l) row (16384 blocks x 256 threads).
//  Row = 64x64 floats = 1024 float4. Thread covers idx = k*256+tid, k<4.
//  - j4 = idx & 15 = tid & 15  -> iteration-INVARIANT: emission float4
//    loaded ONCE per thread, reused across all 4 stores.
//  - transition idx = k*256+tid -> block-invariant, L1-resident after the
//    first block on each CU (16 KiB table).
//  - stores: consecutive lanes -> consecutive 16B, nontemporal (256 MiB
//    >> 32 MiB L2, don't thrash dirty lines).

typedef float v4f __attribute__((ext_vector_type(4)));

__global__ __launch_bounds__(256) void crf_scores_kernel(
    const float* __restrict__ emission,   // [B*L, 64]  (v4f view: [B*L, 16])
    const float* __restrict__ transition, // [64, 64]   (v4f view: [1024])
    float* __restrict__ out)              // [B*L, 64, 64] (v4f view)
{
    const v4f* __restrict__ em4 = reinterpret_cast<const v4f*>(emission);
    const v4f* __restrict__ tr4 = reinterpret_cast<const v4f*>(transition);
    v4f* __restrict__ out4 = reinterpret_cast<v4f*>(out);

    const unsigned int bl  = blockIdx.x;          // (b*L + l) row, < 16384
    const unsigned int tid = threadIdx.x;         // < 256

    // emission float4 for this thread's j-group: invariant across k
    v4f e = em4[(bl << 4) | (tid & 15u)];

    v4f* __restrict__ orow = out4 + ((size_t)bl << 10); // 1024 float4 per row

#pragma unroll
    for (unsigned int k = 0; k < 4; ++k) {
        unsigned int idx = (k << 8) | tid;        // < 1024, i = idx>>4, j4 = idx&15
        v4f tv = tr4[idx];
        v4f r  = e + tv;
        __builtin_nontemporal_store(r, &orow[idx]);
    }
}

extern "C" void kernel_launch(void* const* d_in, const int* in_sizes, int n_in,
                              void* d_out, int out_size, void* d_ws, size_t ws_size,
                              hipStream_t stream) {
    const float* emission   = (const float*)d_in[0]; // [32, 512, 64]
    const float* transition = (const float*)d_in[1]; // [64, 64]
    float* out = (float*)d_out;                      // [32, 512, 64, 64]

    const int block = 256;
    const int grid = 32 * 512;   // one block per (b,l) row

    crf_scores_kernel<<<grid, block, 0, stream>>>(emission, transition, out);
}